// Round 2
// baseline (5298.328 us; speedup 1.0000x reference)
//
#include <hip/hip_runtime.h>
#include <cstdint>
#include <cstddef>

// Problem constants
#define B_  512
#define T_  256
#define D_  256
#define H_  1024
#define K2  512      // effective K = 2*D (x_tilde | m); xm middle third folded into cvec
#define N2  2048     // stacked outputs: [0,1024)=z preact, [1024,2048)=h_til preact
#define TC  32       // timesteps per chunk
#define NCHUNK 8     // TC*NCHUNK == T_

// Workspace layout (bytes). Total ~88 MB (known to fit from round 1).
#define OFF_WB    ((size_t)0)                      // bf16 [2048][512]            2 MB
#define OFF_CVEC  ((size_t)2097152)                // f32  [2048]                 8 KB
#define OFF_H     ((size_t)2105344)                // f32  [B][H]                 2 MB
#define OFF_INP2  ((size_t)4202496)                // bf16 [TC*B][512]           16 MB
#define OFF_GATES ((size_t)20979712)               // bf16 [TC*B][2048]          64 MB

typedef short   bf16x8 __attribute__((ext_vector_type(8)));   // 8 bf16 (4 VGPRs)
typedef float   f32x4  __attribute__((ext_vector_type(4)));

__device__ __forceinline__ unsigned short f2bf(float f) {
    unsigned int u = __float_as_uint(f);
    u += 0x7fffu + ((u >> 16) & 1u);   // round-to-nearest-even
    return (unsigned short)(u >> 16);
}
__device__ __forceinline__ float bf2f(unsigned short s) {
    return __uint_as_float(((unsigned int)s) << 16);
}
__device__ __forceinline__ void async16(const void* g, void* l) {
    __builtin_amdgcn_global_load_lds(
        (const __attribute__((address_space(1))) void*)g,
        (__attribute__((address_space(3))) void*)l, 16, 0, 0);
}

// ---- Prep: pack effective weight columns [0:D) and [2D:3D) to bf16 [2048][512] ----
__global__ void build_wb(const float* __restrict__ Wz, const float* __restrict__ Wh,
                         unsigned short* __restrict__ Wb) {
    int e = blockIdx.x * 256 + threadIdx.x;
    int r = e >> 9;
    int k = e & 511;
    int col = (k < D_) ? k : (k + D_);             // skip the xm middle third
    float v = (r < H_) ? Wz[(size_t)r * 768 + col]
                       : Wh[(size_t)(r - H_) * 768 + col];
    Wb[e] = f2bf(v);
}

// ---- Prep: cvec[r] = bias[r] + W[r, D:2D] . xm ----
__global__ void build_cvec(const float* __restrict__ Wz, const float* __restrict__ bz,
                           const float* __restrict__ Wh, const float* __restrict__ bh,
                           const float* __restrict__ xm, float* __restrict__ cvec) {
    int r = blockIdx.x;           // 0..2047
    int d = threadIdx.x;          // 0..255
    const float* W = (r < H_) ? (Wz + (size_t)r * 768) : (Wh + (size_t)(r - H_) * 768);
    float v = W[D_ + d] * xm[d];
    for (int off = 32; off; off >>= 1) v += __shfl_down(v, off);
    __shared__ float red[4];
    if ((d & 63) == 0) red[d >> 6] = v;
    __syncthreads();
    if (d == 0) {
        float bias = (r < H_) ? bz[r] : bh[r - H_];
        cvec[r] = bias + red[0] + red[1] + red[2] + red[3];
    }
}

// ---- Per-chunk: build bf16 inp2 rows (r = tc*B + b): [x_tilde(0:256) | m(0:256)] ----
__global__ void build_inp2(const float* __restrict__ X, const float* __restrict__ Mm,
                           const float* __restrict__ xm, const float* __restrict__ gx,
                           unsigned short* __restrict__ inp2, int chunk) {
    int g = blockIdx.x * 256 + threadIdx.x;        // vec8 id; total TC*B*64
    int r = g >> 6;
    int k = (g & 63) * 8;
    int tc = r >> 9;
    int b  = r & (B_ - 1);
    int t  = chunk * TC + tc;
    unsigned short o[8];
    if (k < D_) {
        int d = k;
        const float4* xp = (const float4*)(X  + ((size_t)b * T_ + t) * D_ + d);
        const float4* mp = (const float4*)(Mm + ((size_t)b * T_ + t) * D_ + d);
        float xs[8], ms[8];
        float4 v;
        v = xp[0]; xs[0]=v.x; xs[1]=v.y; xs[2]=v.z; xs[3]=v.w;
        v = xp[1]; xs[4]=v.x; xs[5]=v.y; xs[6]=v.z; xs[7]=v.w;
        v = mp[0]; ms[0]=v.x; ms[1]=v.y; ms[2]=v.z; ms[3]=v.w;
        v = mp[1]; ms[4]=v.x; ms[5]=v.y; ms[6]=v.z; ms[7]=v.w;
        #pragma unroll
        for (int j = 0; j < 8; j++) {
            float m = ms[j], x = xs[j], mu = xm[d + j], gg = gx[d + j];
            float xh = m * x + (1.f - m) * mu;
            float gd = __expf(-gg * (1.f - m));
            o[j] = f2bf(gd * xh + (1.f - gd) * mu);
        }
    } else {
        int d = k - D_;
        const float4* mp = (const float4*)(Mm + ((size_t)b * T_ + t) * D_ + d);
        float4 m0 = mp[0], m1 = mp[1];
        o[0]=f2bf(m0.x); o[1]=f2bf(m0.y); o[2]=f2bf(m0.z); o[3]=f2bf(m0.w);
        o[4]=f2bf(m1.x); o[5]=f2bf(m1.y); o[6]=f2bf(m1.z); o[7]=f2bf(m1.w);
    }
    uint4 pk;
    pk.x = (unsigned)o[0] | ((unsigned)o[1] << 16);
    pk.y = (unsigned)o[2] | ((unsigned)o[3] << 16);
    pk.z = (unsigned)o[4] | ((unsigned)o[5] << 16);
    pk.w = (unsigned)o[6] | ((unsigned)o[7] << 16);
    *(uint4*)(inp2 + (size_t)r * K2 + k) = pk;
}

// ---- GEMM: gates[r][n] = act(inp2[r,:] . Wb[n,:] + cvec[n]) ----
// m97-style: 128x128 tile, BK=32, global_load_lds width=16, 16x16x32 bf16 MFMA.
// Epilogue: fp32 tile through LDS (4 passes of 32x128, stride 132 to break bank
// power-of-2), activation on read side, coalesced 32 B/thread dwordx4 stores.
// grid = (Mrows/128, 16); tn<8 -> sigmoid (z), tn>=8 -> tanh (h_til).
__global__ __launch_bounds__(256, 4) void gemm_gates(
    const unsigned short* __restrict__ A,      // [TC*B][512] bf16
    const unsigned short* __restrict__ W,      // [2048][512] bf16
    const float* __restrict__ cvec,            // [2048]
    unsigned short* __restrict__ gates)        // [TC*B][2048] bf16
{
    // union: K-loop uses As/Bs (16384 B); epilogue reuses as Cs fp32 [32][132] (16896 B)
    __shared__ __align__(16) char smem[32 * 132 * 4];
    unsigned short* As = (unsigned short*)smem;
    unsigned short* Bs = As + 128 * 32;
    float* Cs = (float*)smem;

    const int tid  = threadIdx.x;
    const int lane = tid & 63;
    const int w    = tid >> 6;
    const int tm = blockIdx.x, tn = blockIdx.y;
    const int wm = w & 1, wn = w >> 1;

    // staging: 8 segments of 16 rows x 32 cols (1 KB each); wave w does segs {2w, 2w+1}
    const int seg  = w * 2;
    const int srow = seg * 16 + (lane >> 2);
    const int scol = (lane & 3) * 8;
    const unsigned short* aptr = A + (size_t)(tm * 128 + srow) * K2 + scol;
    const unsigned short* bptr = W + (size_t)(tn * 128 + srow) * K2 + scol;
    unsigned short* adst = &As[seg * 16 * 32];
    unsigned short* bdst = &Bs[seg * 16 * 32];

    f32x4 acc[4][4] = {};

    for (int k0 = 0; k0 < K2; k0 += 32) {
        __syncthreads();
        async16(aptr + k0,           adst);
        async16(aptr + 16*K2 + k0,   adst + 16*32);
        async16(bptr + k0,           bdst);
        async16(bptr + 16*K2 + k0,   bdst + 16*32);
        __syncthreads();   // compiler drains vmcnt before s_barrier
        bf16x8 af[4], bfr[4];
        #pragma unroll
        for (int i = 0; i < 4; i++)
            af[i] = *(const bf16x8*)&As[(wm*64 + i*16 + (lane & 15)) * 32 + (lane >> 4) * 8];
        #pragma unroll
        for (int j = 0; j < 4; j++)
            bfr[j] = *(const bf16x8*)&Bs[(wn*64 + j*16 + (lane & 15)) * 32 + (lane >> 4) * 8];
        #pragma unroll
        for (int i = 0; i < 4; i++)
            #pragma unroll
            for (int j = 0; j < 4; j++)
                acc[i][j] = __builtin_amdgcn_mfma_f32_16x16x32_bf16(af[i], bfr[j], acc[i][j], 0, 0, 0);
    }

    const bool is_z = (tn < 8);    // block-uniform: which activation
    const int rl  = tid >> 3;          // 0..31  (read-side row within pass)
    const int cb  = (tid & 7) * 16;    // 0..112 (read-side col base, 16 floats)
    #pragma unroll 1
    for (int p = 0; p < 4; p++) {
        __syncthreads();               // also protects As/Bs reuse on p==0
        if (wm == (p >> 1)) {
            #pragma unroll
            for (int il = 0; il < 2; il++) {
                const int i = (p & 1) * 2 + il;
                #pragma unroll
                for (int j = 0; j < 4; j++) {
                    const int col = wn * 64 + j * 16 + (lane & 15);
                    const int rb  = il * 16 + (lane >> 4) * 4;
                    #pragma unroll
                    for (int r = 0; r < 4; r++)
                        Cs[(rb + r) * 132 + col] = acc[i][j][r];
                }
            }
        }
        __syncthreads();
        // read 32x128 fp32, add cvec, activate, pack bf16, coalesced store
        unsigned short tmp[16];
        #pragma unroll
        for (int k = 0; k < 4; k++) {
            f32x4  v  = *(const f32x4*)&Cs[rl * 132 + cb + k * 4];
            float4 cv = *(const float4*)&cvec[tn * 128 + cb + k * 4];
            float vv[4] = { v[0] + cv.x, v[1] + cv.y, v[2] + cv.z, v[3] + cv.w };
            #pragma unroll
            for (int e = 0; e < 4; e++) {
                float u = vv[e];
                if (is_z) u = 1.f / (1.f + __expf(-u));
                else      u = 2.f / (1.f + __expf(-2.f * u)) - 1.f;
                tmp[k * 4 + e] = f2bf(u);
            }
        }
        uint4 pk0, pk1;
        pk0.x = (unsigned)tmp[0]  | ((unsigned)tmp[1]  << 16);
        pk0.y = (unsigned)tmp[2]  | ((unsigned)tmp[3]  << 16);
        pk0.z = (unsigned)tmp[4]  | ((unsigned)tmp[5]  << 16);
        pk0.w = (unsigned)tmp[6]  | ((unsigned)tmp[7]  << 16);
        pk1.x = (unsigned)tmp[8]  | ((unsigned)tmp[9]  << 16);
        pk1.y = (unsigned)tmp[10] | ((unsigned)tmp[11] << 16);
        pk1.z = (unsigned)tmp[12] | ((unsigned)tmp[13] << 16);
        pk1.w = (unsigned)tmp[14] | ((unsigned)tmp[15] << 16);
        const int grow = tm * 128 + p * 32 + rl;
        unsigned short* gp = gates + (size_t)grow * N2 + tn * 128 + cb;
        *(uint4*)gp       = pk0;
        *(uint4*)(gp + 8) = pk1;
    }
}

// ---- Per-chunk elementwise scan: h = (1-z)*h + z*h_til over TC steps ----
__global__ void recurrence(const unsigned short* __restrict__ gates,
                           float* __restrict__ hbuf, int first) {
    const int g  = blockIdx.x * 256 + threadIdx.x;   // B*H/2 threads
    const int b  = g >> 9;
    const int nb = (g & 511) * 2;
    float h0, h1;
    if (first) { h0 = 0.f; h1 = 0.f; }
    else { float2 hv = *(const float2*)&hbuf[(size_t)b * H_ + nb]; h0 = hv.x; h1 = hv.y; }
    for (int tc = 0; tc < TC; tc++) {
        const unsigned short* base = gates + (size_t)(tc * B_ + b) * N2;
        unsigned int zz = *(const unsigned int*)(base + nb);
        unsigned int hh = *(const unsigned int*)(base + H_ + nb);
        float z0 = bf2f((unsigned short)(zz & 0xffff));
        float z1 = bf2f((unsigned short)(zz >> 16));
        float t0 = bf2f((unsigned short)(hh & 0xffff));
        float t1 = bf2f((unsigned short)(hh >> 16));
        h0 = (1.f - z0) * h0 + z0 * t0;
        h1 = (1.f - z1) * h1 + z1 * t1;
    }
    *(float2*)&hbuf[(size_t)b * H_ + nb] = make_float2(h0, h1);
}

// ---- Output head: out[b] = sigmoid(h[b,:] . Wout + bout) ----
__global__ void head(const float* __restrict__ hbuf, const float* __restrict__ Wout,
                     const float* __restrict__ bout, float* __restrict__ out) {
    int b = blockIdx.x;
    float s = 0.f;
    for (int n = threadIdx.x; n < H_; n += 256)
        s += hbuf[(size_t)b * H_ + n] * Wout[n];
    for (int off = 32; off; off >>= 1) s += __shfl_down(s, off);
    __shared__ float red[4];
    if ((threadIdx.x & 63) == 0) red[threadIdx.x >> 6] = s;
    __syncthreads();
    if (threadIdx.x == 0) {
        float t = red[0] + red[1] + red[2] + red[3] + bout[0];
        out[b] = 1.f / (1.f + expf(-t));
    }
}

extern "C" void kernel_launch(void* const* d_in, const int* in_sizes, int n_in,
                              void* d_out, int out_size, void* d_ws, size_t ws_size,
                              hipStream_t stream) {
    const float* X    = (const float*)d_in[0];
    const float* Mm   = (const float*)d_in[1];
    const float* xm   = (const float*)d_in[2];
    const float* gx   = (const float*)d_in[3];
    const float* Wz   = (const float*)d_in[4];
    const float* bz   = (const float*)d_in[5];
    // d_in[6]=Wr, d_in[7]=br: dead code in reference (r_t unused) — skipped
    const float* Wh   = (const float*)d_in[8];
    const float* bh   = (const float*)d_in[9];
    const float* Wout = (const float*)d_in[10];
    const float* bout = (const float*)d_in[11];
    float* out = (float*)d_out;

    char* ws = (char*)d_ws;
    unsigned short* Wb    = (unsigned short*)(ws + OFF_WB);
    float*          cvec  = (float*)(ws + OFF_CVEC);
    float*          hbuf  = (float*)(ws + OFF_H);
    unsigned short* inp2  = (unsigned short*)(ws + OFF_INP2);
    unsigned short* gates = (unsigned short*)(ws + OFF_GATES);

    build_wb  <<<dim3(N2 * K2 / 256), dim3(256), 0, stream>>>(Wz, Wh, Wb);
    build_cvec<<<dim3(N2),            dim3(256), 0, stream>>>(Wz, bz, Wh, bh, xm, cvec);

    for (int c = 0; c < NCHUNK; c++) {
        build_inp2<<<dim3(TC * B_ * 64 / 256), dim3(256), 0, stream>>>(X, Mm, xm, gx, inp2, c);
        gemm_gates<<<dim3(TC * B_ / 128, 16),  dim3(256), 0, stream>>>(inp2, Wb, cvec, gates);
        recurrence<<<dim3(B_ * H_ / 2 / 256),  dim3(256), 0, stream>>>(gates, hbuf, c == 0 ? 1 : 0);
    }

    head<<<dim3(B_), dim3(256), 0, stream>>>(hbuf, Wout, bout, out);
}

// Round 3
// 1052.359 us; speedup vs baseline: 5.0347x; 5.0347x over previous
//
#include <hip/hip_runtime.h>
#include <cstdint>
#include <cstddef>

// Problem constants
#define B_  512
#define T_  256
#define D_  256
#define H_  1024
#define K2  512      // effective K = 2*D (x_tilde | m); xm middle third folded into cvec
#define N2  2048     // stacked outputs: [0,1024)=z preact, [1024,2048)=h_til preact
#define TC  32       // timesteps per chunk
#define NCHUNK 8     // TC*NCHUNK == T_

// Workspace layout (bytes). Total ~88 MB.
#define OFF_WB    ((size_t)0)                      // bf16 [2048][512]            2 MB
#define OFF_CVEC  ((size_t)2097152)                // f32  [2048]                 8 KB
#define OFF_H     ((size_t)2105344)                // f32  [B][H]                 2 MB
#define OFF_INP2  ((size_t)4202496)                // bf16 [TC*B][512]           16 MB
#define OFF_GATES ((size_t)20979712)               // bf16 [TC*B][2048]          64 MB

typedef short   bf16x8 __attribute__((ext_vector_type(8)));   // 8 bf16 (4 VGPRs)
typedef float   f32x4  __attribute__((ext_vector_type(4)));

__device__ __forceinline__ unsigned short f2bf(float f) {
    unsigned int u = __float_as_uint(f);
    u += 0x7fffu + ((u >> 16) & 1u);   // round-to-nearest-even
    return (unsigned short)(u >> 16);
}
__device__ __forceinline__ float bf2f(unsigned short s) {
    return __uint_as_float(((unsigned int)s) << 16);
}
__device__ __forceinline__ void async16(const void* g, void* l) {
    __builtin_amdgcn_global_load_lds(
        (const __attribute__((address_space(1))) void*)g,
        (__attribute__((address_space(3))) void*)l, 16, 0, 0);
}

// ---- Prep: pack effective weight columns [0:D) and [2D:3D) to bf16 [2048][512] ----
__global__ void build_wb(const float* __restrict__ Wz, const float* __restrict__ Wh,
                         unsigned short* __restrict__ Wb) {
    int e = blockIdx.x * 256 + threadIdx.x;
    int r = e >> 9;
    int k = e & 511;
    int col = (k < D_) ? k : (k + D_);             // skip the xm middle third
    float v = (r < H_) ? Wz[(size_t)r * 768 + col]
                       : Wh[(size_t)(r - H_) * 768 + col];
    Wb[e] = f2bf(v);
}

// ---- Prep: cvec[r] = bias[r] + W[r, D:2D] . xm ----
__global__ void build_cvec(const float* __restrict__ Wz, const float* __restrict__ bz,
                           const float* __restrict__ Wh, const float* __restrict__ bh,
                           const float* __restrict__ xm, float* __restrict__ cvec) {
    int r = blockIdx.x;           // 0..2047
    int d = threadIdx.x;          // 0..255
    const float* W = (r < H_) ? (Wz + (size_t)r * 768) : (Wh + (size_t)(r - H_) * 768);
    float v = W[D_ + d] * xm[d];
    for (int off = 32; off; off >>= 1) v += __shfl_down(v, off);
    __shared__ float red[4];
    if ((d & 63) == 0) red[d >> 6] = v;
    __syncthreads();
    if (d == 0) {
        float bias = (r < H_) ? bz[r] : bh[r - H_];
        cvec[r] = bias + red[0] + red[1] + red[2] + red[3];
    }
}

// ---- Per-chunk: build bf16 inp2 rows (r = tc*B + b): [x_tilde(0:256) | m(0:256)] ----
__global__ void build_inp2(const float* __restrict__ X, const float* __restrict__ Mm,
                           const float* __restrict__ xm, const float* __restrict__ gx,
                           unsigned short* __restrict__ inp2, int chunk) {
    int g = blockIdx.x * 256 + threadIdx.x;        // vec8 id; total TC*B*64
    int r = g >> 6;
    int k = (g & 63) * 8;
    int tc = r >> 9;
    int b  = r & (B_ - 1);
    int t  = chunk * TC + tc;
    unsigned short o[8];
    if (k < D_) {
        int d = k;
        const float4* xp = (const float4*)(X  + ((size_t)b * T_ + t) * D_ + d);
        const float4* mp = (const float4*)(Mm + ((size_t)b * T_ + t) * D_ + d);
        float xs[8], ms[8];
        float4 v;
        v = xp[0]; xs[0]=v.x; xs[1]=v.y; xs[2]=v.z; xs[3]=v.w;
        v = xp[1]; xs[4]=v.x; xs[5]=v.y; xs[6]=v.z; xs[7]=v.w;
        v = mp[0]; ms[0]=v.x; ms[1]=v.y; ms[2]=v.z; ms[3]=v.w;
        v = mp[1]; ms[4]=v.x; ms[5]=v.y; ms[6]=v.z; ms[7]=v.w;
        #pragma unroll
        for (int j = 0; j < 8; j++) {
            float m = ms[j], x = xs[j], mu = xm[d + j], gg = gx[d + j];
            float xh = m * x + (1.f - m) * mu;
            float gd = __expf(-gg * (1.f - m));
            o[j] = f2bf(gd * xh + (1.f - gd) * mu);
        }
    } else {
        int d = k - D_;
        const float4* mp = (const float4*)(Mm + ((size_t)b * T_ + t) * D_ + d);
        float4 m0 = mp[0], m1 = mp[1];
        o[0]=f2bf(m0.x); o[1]=f2bf(m0.y); o[2]=f2bf(m0.z); o[3]=f2bf(m0.w);
        o[4]=f2bf(m1.x); o[5]=f2bf(m1.y); o[6]=f2bf(m1.z); o[7]=f2bf(m1.w);
    }
    uint4 pk;
    pk.x = (unsigned)o[0] | ((unsigned)o[1] << 16);
    pk.y = (unsigned)o[2] | ((unsigned)o[3] << 16);
    pk.z = (unsigned)o[4] | ((unsigned)o[5] << 16);
    pk.w = (unsigned)o[6] | ((unsigned)o[7] << 16);
    *(uint4*)(inp2 + (size_t)r * K2 + k) = pk;
}

// ---- GEMM: gates[r][n] = act(inp2[r,:] . Wb[n,:] + cvec[n]) ----
// m97-style: 128x128 tile, BK=32, global_load_lds width=16, 16x16x32 bf16 MFMA.
// Epilogue: fp32 tile through LDS in 4 FULLY-UNROLLED passes of 32x128
// (stride 132 breaks bank power-of-2); all acc[][] indices compile-time
// constant (runtime indices spilled the accumulator to scratch in round 2:
// VGPR 80->48, 3.2 GB/dispatch scratch traffic). Coalesced 32 B/thread stores.
// grid = (Mrows/128, 16); tn<8 -> sigmoid (z), tn>=8 -> tanh (h_til).
__global__ __launch_bounds__(256) void gemm_gates(
    const unsigned short* __restrict__ A,      // [TC*B][512] bf16
    const unsigned short* __restrict__ W,      // [2048][512] bf16
    const float* __restrict__ cvec,            // [2048]
    unsigned short* __restrict__ gates)        // [TC*B][2048] bf16
{
    // union: K-loop uses As/Bs (16384 B); epilogue reuses as Cs fp32 [32][132]
    __shared__ __align__(16) char smem[32 * 132 * 4];
    unsigned short* As = (unsigned short*)smem;
    unsigned short* Bs = As + 128 * 32;
    float* Cs = (float*)smem;

    const int tid  = threadIdx.x;
    const int lane = tid & 63;
    const int w    = tid >> 6;
    const int tm = blockIdx.x, tn = blockIdx.y;
    const int wm = w & 1, wn = w >> 1;

    // staging: 8 segments of 16 rows x 32 cols (1 KB each); wave w does segs {2w, 2w+1}
    const int seg  = w * 2;
    const int srow = seg * 16 + (lane >> 2);
    const int scol = (lane & 3) * 8;
    const unsigned short* aptr = A + (size_t)(tm * 128 + srow) * K2 + scol;
    const unsigned short* bptr = W + (size_t)(tn * 128 + srow) * K2 + scol;
    unsigned short* adst = &As[seg * 16 * 32];
    unsigned short* bdst = &Bs[seg * 16 * 32];

    f32x4 acc[4][4] = {};

    for (int k0 = 0; k0 < K2; k0 += 32) {
        __syncthreads();
        async16(aptr + k0,           adst);
        async16(aptr + 16*K2 + k0,   adst + 16*32);
        async16(bptr + k0,           bdst);
        async16(bptr + 16*K2 + k0,   bdst + 16*32);
        __syncthreads();   // compiler drains vmcnt before s_barrier
        bf16x8 af[4], bfr[4];
        #pragma unroll
        for (int i = 0; i < 4; i++)
            af[i] = *(const bf16x8*)&As[(wm*64 + i*16 + (lane & 15)) * 32 + (lane >> 4) * 8];
        #pragma unroll
        for (int j = 0; j < 4; j++)
            bfr[j] = *(const bf16x8*)&Bs[(wn*64 + j*16 + (lane & 15)) * 32 + (lane >> 4) * 8];
        #pragma unroll
        for (int i = 0; i < 4; i++)
            #pragma unroll
            for (int j = 0; j < 4; j++)
                acc[i][j] = __builtin_amdgcn_mfma_f32_16x16x32_bf16(af[i], bfr[j], acc[i][j], 0, 0, 0);
    }

    const bool is_z = (tn < 8);        // block-uniform: which activation
    const int rl  = tid >> 3;          // 0..31  (read-side row within pass)
    const int cb  = (tid & 7) * 16;    // 0..112 (read-side col base, 16 floats)
    #pragma unroll
    for (int p = 0; p < 4; p++) {      // FULLY unrolled: acc indices constant
        __syncthreads();               // also protects As/Bs reuse on p==0
        if (wm == (p >> 1)) {
            #pragma unroll
            for (int il = 0; il < 2; il++) {
                const int i = (p & 1) * 2 + il;
                #pragma unroll
                for (int j = 0; j < 4; j++) {
                    const int col = wn * 64 + j * 16 + (lane & 15);
                    const int rb  = il * 16 + (lane >> 4) * 4;
                    #pragma unroll
                    for (int r = 0; r < 4; r++)
                        Cs[(rb + r) * 132 + col] = acc[i][j][r];
                }
            }
        }
        __syncthreads();
        // read 32x128 fp32, add cvec, activate, pack bf16, coalesced store
        unsigned short tmp[16];
        #pragma unroll
        for (int k = 0; k < 4; k++) {
            f32x4  v  = *(const f32x4*)&Cs[rl * 132 + cb + k * 4];
            float4 cv = *(const float4*)&cvec[tn * 128 + cb + k * 4];
            float vv[4] = { v[0] + cv.x, v[1] + cv.y, v[2] + cv.z, v[3] + cv.w };
            #pragma unroll
            for (int e = 0; e < 4; e++) {
                float u = vv[e];
                if (is_z) u = 1.f / (1.f + __expf(-u));
                else      u = 2.f / (1.f + __expf(-2.f * u)) - 1.f;
                tmp[k * 4 + e] = f2bf(u);
            }
        }
        uint4 pk0, pk1;
        pk0.x = (unsigned)tmp[0]  | ((unsigned)tmp[1]  << 16);
        pk0.y = (unsigned)tmp[2]  | ((unsigned)tmp[3]  << 16);
        pk0.z = (unsigned)tmp[4]  | ((unsigned)tmp[5]  << 16);
        pk0.w = (unsigned)tmp[6]  | ((unsigned)tmp[7]  << 16);
        pk1.x = (unsigned)tmp[8]  | ((unsigned)tmp[9]  << 16);
        pk1.y = (unsigned)tmp[10] | ((unsigned)tmp[11] << 16);
        pk1.z = (unsigned)tmp[12] | ((unsigned)tmp[13] << 16);
        pk1.w = (unsigned)tmp[14] | ((unsigned)tmp[15] << 16);
        const int grow = tm * 128 + p * 32 + rl;
        unsigned short* gp = gates + (size_t)grow * N2 + tn * 128 + cb;
        *(uint4*)gp       = pk0;
        *(uint4*)(gp + 8) = pk1;
    }
}

// ---- Per-chunk elementwise scan: h = (1-z)*h + z*h_til over TC steps ----
__global__ void recurrence(const unsigned short* __restrict__ gates,
                           float* __restrict__ hbuf, int first) {
    const int g  = blockIdx.x * 256 + threadIdx.x;   // B*H/2 threads
    const int b  = g >> 9;
    const int nb = (g & 511) * 2;
    float h0, h1;
    if (first) { h0 = 0.f; h1 = 0.f; }
    else { float2 hv = *(const float2*)&hbuf[(size_t)b * H_ + nb]; h0 = hv.x; h1 = hv.y; }
    for (int tc = 0; tc < TC; tc++) {
        const unsigned short* base = gates + (size_t)(tc * B_ + b) * N2;
        unsigned int zz = *(const unsigned int*)(base + nb);
        unsigned int hh = *(const unsigned int*)(base + H_ + nb);
        float z0 = bf2f((unsigned short)(zz & 0xffff));
        float z1 = bf2f((unsigned short)(zz >> 16));
        float t0 = bf2f((unsigned short)(hh & 0xffff));
        float t1 = bf2f((unsigned short)(hh >> 16));
        h0 = (1.f - z0) * h0 + z0 * t0;
        h1 = (1.f - z1) * h1 + z1 * t1;
    }
    *(float2*)&hbuf[(size_t)b * H_ + nb] = make_float2(h0, h1);
}

// ---- Output head: out[b] = sigmoid(h[b,:] . Wout + bout) ----
__global__ void head(const float* __restrict__ hbuf, const float* __restrict__ Wout,
                     const float* __restrict__ bout, float* __restrict__ out) {
    int b = blockIdx.x;
    float s = 0.f;
    for (int n = threadIdx.x; n < H_; n += 256)
        s += hbuf[(size_t)b * H_ + n] * Wout[n];
    for (int off = 32; off; off >>= 1) s += __shfl_down(s, off);
    __shared__ float red[4];
    if ((threadIdx.x & 63) == 0) red[threadIdx.x >> 6] = s;
    __syncthreads();
    if (threadIdx.x == 0) {
        float t = red[0] + red[1] + red[2] + red[3] + bout[0];
        out[b] = 1.f / (1.f + expf(-t));
    }
}

extern "C" void kernel_launch(void* const* d_in, const int* in_sizes, int n_in,
                              void* d_out, int out_size, void* d_ws, size_t ws_size,
                              hipStream_t stream) {
    const float* X    = (const float*)d_in[0];
    const float* Mm   = (const float*)d_in[1];
    const float* xm   = (const float*)d_in[2];
    const float* gx   = (const float*)d_in[3];
    const float* Wz   = (const float*)d_in[4];
    const float* bz   = (const float*)d_in[5];
    // d_in[6]=Wr, d_in[7]=br: dead code in reference (r_t unused) — skipped
    const float* Wh   = (const float*)d_in[8];
    const float* bh   = (const float*)d_in[9];
    const float* Wout = (const float*)d_in[10];
    const float* bout = (const float*)d_in[11];
    float* out = (float*)d_out;

    char* ws = (char*)d_ws;
    unsigned short* Wb    = (unsigned short*)(ws + OFF_WB);
    float*          cvec  = (float*)(ws + OFF_CVEC);
    float*          hbuf  = (float*)(ws + OFF_H);
    unsigned short* inp2  = (unsigned short*)(ws + OFF_INP2);
    unsigned short* gates = (unsigned short*)(ws + OFF_GATES);

    build_wb  <<<dim3(N2 * K2 / 256), dim3(256), 0, stream>>>(Wz, Wh, Wb);
    build_cvec<<<dim3(N2),            dim3(256), 0, stream>>>(Wz, bz, Wh, bh, xm, cvec);

    for (int c = 0; c < NCHUNK; c++) {
        build_inp2<<<dim3(TC * B_ * 64 / 256), dim3(256), 0, stream>>>(X, Mm, xm, gx, inp2, c);
        gemm_gates<<<dim3(TC * B_ / 128, 16),  dim3(256), 0, stream>>>(inp2, Wb, cvec, gates);
        recurrence<<<dim3(B_ * H_ / 2 / 256),  dim3(256), 0, stream>>>(gates, hbuf, c == 0 ? 1 : 0);
    }

    head<<<dim3(B_), dim3(256), 0, stream>>>(hbuf, Wout, bout, out);
}

// Round 4
// 949.081 us; speedup vs baseline: 5.5826x; 1.1088x over previous
//
#include <hip/hip_runtime.h>
#include <cstdint>
#include <cstddef>

// Problem constants
#define B_  512
#define T_  256
#define D_  256
#define H_  1024
#define K2  512      // effective K = 2*D (x_tilde | m); xm middle third folded into cvec
#define N2  2048     // stacked outputs: [0,1024)=z preact, [1024,2048)=h_til preact
#define TC  32       // timesteps per chunk
#define NCHUNK 8     // TC*NCHUNK == T_

// Workspace layout (bytes). Total ~88 MB.
#define OFF_WB    ((size_t)0)                      // bf16 [2048][512]            2 MB
#define OFF_CVEC  ((size_t)2097152)                // f32  [2048]                 8 KB
#define OFF_H     ((size_t)2105344)                // f32  [B][H]                 2 MB
#define OFF_INP2  ((size_t)4202496)                // bf16 [TC*B][512]           16 MB
#define OFF_GATES ((size_t)20979712)               // bf16 [TC*B][2048]          64 MB

typedef short   bf16x8 __attribute__((ext_vector_type(8)));   // 8 bf16 (4 VGPRs)
typedef float   f32x4  __attribute__((ext_vector_type(4)));

__device__ __forceinline__ unsigned short f2bf(float f) {
    unsigned int u = __float_as_uint(f);
    u += 0x7fffu + ((u >> 16) & 1u);   // round-to-nearest-even
    return (unsigned short)(u >> 16);
}
__device__ __forceinline__ float bf2f(unsigned short s) {
    return __uint_as_float(((unsigned int)s) << 16);
}
__device__ __forceinline__ void async16(const void* g, void* l) {
    __builtin_amdgcn_global_load_lds(
        (const __attribute__((address_space(1))) void*)g,
        (__attribute__((address_space(3))) void*)l, 16, 0, 0);
}

// ---- Prep: pack effective weight columns [0:D) and [2D:3D) to bf16 [2048][512] ----
__global__ void build_wb(const float* __restrict__ Wz, const float* __restrict__ Wh,
                         unsigned short* __restrict__ Wb) {
    int e = blockIdx.x * 256 + threadIdx.x;
    int r = e >> 9;
    int k = e & 511;
    int col = (k < D_) ? k : (k + D_);             // skip the xm middle third
    float v = (r < H_) ? Wz[(size_t)r * 768 + col]
                       : Wh[(size_t)(r - H_) * 768 + col];
    Wb[e] = f2bf(v);
}

// ---- Prep: cvec[r] = bias[r] + W[r, D:2D] . xm ----
__global__ void build_cvec(const float* __restrict__ Wz, const float* __restrict__ bz,
                           const float* __restrict__ Wh, const float* __restrict__ bh,
                           const float* __restrict__ xm, float* __restrict__ cvec) {
    int r = blockIdx.x;           // 0..2047
    int d = threadIdx.x;          // 0..255
    const float* W = (r < H_) ? (Wz + (size_t)r * 768) : (Wh + (size_t)(r - H_) * 768);
    float v = W[D_ + d] * xm[d];
    for (int off = 32; off; off >>= 1) v += __shfl_down(v, off);
    __shared__ float red[4];
    if ((d & 63) == 0) red[d >> 6] = v;
    __syncthreads();
    if (d == 0) {
        float bias = (r < H_) ? bz[r] : bh[r - H_];
        cvec[r] = bias + red[0] + red[1] + red[2] + red[3];
    }
}

// ---- Per-chunk: build bf16 inp2 rows (r = tc*B + b): [x_tilde(0:256) | m(0:256)] ----
__global__ void build_inp2(const float* __restrict__ X, const float* __restrict__ Mm,
                           const float* __restrict__ xm, const float* __restrict__ gx,
                           unsigned short* __restrict__ inp2, int chunk) {
    int g = blockIdx.x * 256 + threadIdx.x;        // vec8 id; total TC*B*64
    int r = g >> 6;
    int k = (g & 63) * 8;
    int tc = r >> 9;
    int b  = r & (B_ - 1);
    int t  = chunk * TC + tc;
    unsigned short o[8];
    if (k < D_) {
        int d = k;
        const float4* xp = (const float4*)(X  + ((size_t)b * T_ + t) * D_ + d);
        const float4* mp = (const float4*)(Mm + ((size_t)b * T_ + t) * D_ + d);
        float xs[8], ms[8];
        float4 v;
        v = xp[0]; xs[0]=v.x; xs[1]=v.y; xs[2]=v.z; xs[3]=v.w;
        v = xp[1]; xs[4]=v.x; xs[5]=v.y; xs[6]=v.z; xs[7]=v.w;
        v = mp[0]; ms[0]=v.x; ms[1]=v.y; ms[2]=v.z; ms[3]=v.w;
        v = mp[1]; ms[4]=v.x; ms[5]=v.y; ms[6]=v.z; ms[7]=v.w;
        #pragma unroll
        for (int j = 0; j < 8; j++) {
            float m = ms[j], x = xs[j], mu = xm[d + j], gg = gx[d + j];
            float xh = m * x + (1.f - m) * mu;
            float gd = __expf(-gg * (1.f - m));
            o[j] = f2bf(gd * xh + (1.f - gd) * mu);
        }
    } else {
        int d = k - D_;
        const float4* mp = (const float4*)(Mm + ((size_t)b * T_ + t) * D_ + d);
        float4 m0 = mp[0], m1 = mp[1];
        o[0]=f2bf(m0.x); o[1]=f2bf(m0.y); o[2]=f2bf(m0.z); o[3]=f2bf(m0.w);
        o[4]=f2bf(m1.x); o[5]=f2bf(m1.y); o[6]=f2bf(m1.z); o[7]=f2bf(m1.w);
    }
    uint4 pk;
    pk.x = (unsigned)o[0] | ((unsigned)o[1] << 16);
    pk.y = (unsigned)o[2] | ((unsigned)o[3] << 16);
    pk.z = (unsigned)o[4] | ((unsigned)o[5] << 16);
    pk.w = (unsigned)o[6] | ((unsigned)o[7] << 16);
    *(uint4*)(inp2 + (size_t)r * K2 + k) = pk;
}

// ---- GEMM: gates[r][n] = act(inp2[r,:] . Wb[n,:] + cvec[n]) ----
// 128(m) x 256(n) block tile, 4 waves of 64x128 (acc 4x8): 12 ds_read_b128 per
// 32 MFMA per K-iter -> MFMA-bound on the LDS pipe (r3's 4x4 tile was
// LDS-read-bound: 8 reads / 16 MFMA). 1024 blocks (halved) halves per-block
// fixed overhead Phi. BK=32, global_load_lds width=16 staging (6/thread/iter).
// Direct scalar epilogue stores (r1 == r3 showed epilogue style time-neutral).
// grid = (Mrows/128, 8); tn<4 -> sigmoid (z), tn>=4 -> tanh (h_til).
__global__ __launch_bounds__(256, 2) void gemm_gates(
    const unsigned short* __restrict__ A,      // [TC*B][512] bf16
    const unsigned short* __restrict__ W,      // [2048][512] bf16
    const float* __restrict__ cvec,            // [2048]
    unsigned short* __restrict__ gates)        // [TC*B][2048] bf16
{
    __shared__ __align__(16) unsigned short As[128 * 32];   //  8 KB
    __shared__ __align__(16) unsigned short Bs[256 * 32];   // 16 KB

    const int tid  = threadIdx.x;
    const int lane = tid & 63;
    const int w    = tid >> 6;
    const int tm = blockIdx.x, tn = blockIdx.y;
    const int wm = w & 1, wn = w >> 1;

    // staging: segments of 16 rows x 32 k (1 KB, 64 lanes x 16 B).
    // A has 8 segs (wave w: 2w, 2w+1); B has 16 segs (wave w: 4w..4w+3).
    const int srow = lane >> 2;            // row within segment
    const int skof = (lane & 3) * 8;       // k offset (8 shorts = 16 B)
    const unsigned short* aptr = A + (size_t)(tm * 128 + w * 32 + srow) * K2 + skof;
    const unsigned short* bptr = W + (size_t)(tn * 256 + w * 64 + srow) * K2 + skof;
    unsigned short* adst = &As[(w * 2) * 512 + lane * 8];
    unsigned short* bdst = &Bs[(w * 4) * 512 + lane * 8];

    f32x4 acc[4][8] = {};

    for (int k0 = 0; k0 < K2; k0 += 32) {
        __syncthreads();
        async16(aptr + k0,            adst);
        async16(aptr + 16 * K2 + k0,  adst + 512);
        async16(bptr + k0,            bdst);
        async16(bptr + 16 * K2 + k0,  bdst + 512);
        async16(bptr + 32 * K2 + k0,  bdst + 1024);
        async16(bptr + 48 * K2 + k0,  bdst + 1536);
        __syncthreads();   // compiler drains vmcnt before s_barrier
        bf16x8 af[4], bfr[8];
        #pragma unroll
        for (int i = 0; i < 4; i++)
            af[i]  = *(const bf16x8*)&As[(wm * 64  + i * 16 + (lane & 15)) * 32 + (lane >> 4) * 8];
        #pragma unroll
        for (int j = 0; j < 8; j++)
            bfr[j] = *(const bf16x8*)&Bs[(wn * 128 + j * 16 + (lane & 15)) * 32 + (lane >> 4) * 8];
        #pragma unroll
        for (int i = 0; i < 4; i++)
            #pragma unroll
            for (int j = 0; j < 8; j++)
                acc[i][j] = __builtin_amdgcn_mfma_f32_16x16x32_bf16(af[i], bfr[j], acc[i][j], 0, 0, 0);
    }

    const bool is_z = (tn < 4);    // block-uniform: which activation
    #pragma unroll
    for (int j = 0; j < 8; j++) {
        const int ncol = tn * 256 + wn * 128 + j * 16 + (lane & 15);
        const float cadd = cvec[ncol];
        #pragma unroll
        for (int i = 0; i < 4; i++) {
            const int mbase = tm * 128 + wm * 64 + i * 16 + (lane >> 4) * 4;
            #pragma unroll
            for (int r = 0; r < 4; r++) {
                float v = acc[i][j][r] + cadd;
                if (is_z) v = 1.f / (1.f + __expf(-v));
                else      v = 2.f / (1.f + __expf(-2.f * v)) - 1.f;
                gates[(size_t)(mbase + r) * N2 + ncol] = f2bf(v);
            }
        }
    }
}

// ---- Per-chunk elementwise scan: h = (1-z)*h + z*h_til over TC steps ----
__global__ void recurrence(const unsigned short* __restrict__ gates,
                           float* __restrict__ hbuf, int first) {
    const int g  = blockIdx.x * 256 + threadIdx.x;   // B*H/2 threads
    const int b  = g >> 9;
    const int nb = (g & 511) * 2;
    float h0, h1;
    if (first) { h0 = 0.f; h1 = 0.f; }
    else { float2 hv = *(const float2*)&hbuf[(size_t)b * H_ + nb]; h0 = hv.x; h1 = hv.y; }
    for (int tc = 0; tc < TC; tc++) {
        const unsigned short* base = gates + (size_t)(tc * B_ + b) * N2;
        unsigned int zz = *(const unsigned int*)(base + nb);
        unsigned int hh = *(const unsigned int*)(base + H_ + nb);
        float z0 = bf2f((unsigned short)(zz & 0xffff));
        float z1 = bf2f((unsigned short)(zz >> 16));
        float t0 = bf2f((unsigned short)(hh & 0xffff));
        float t1 = bf2f((unsigned short)(hh >> 16));
        h0 = (1.f - z0) * h0 + z0 * t0;
        h1 = (1.f - z1) * h1 + z1 * t1;
    }
    *(float2*)&hbuf[(size_t)b * H_ + nb] = make_float2(h0, h1);
}

// ---- Output head: out[b] = sigmoid(h[b,:] . Wout + bout) ----
__global__ void head(const float* __restrict__ hbuf, const float* __restrict__ Wout,
                     const float* __restrict__ bout, float* __restrict__ out) {
    int b = blockIdx.x;
    float s = 0.f;
    for (int n = threadIdx.x; n < H_; n += 256)
        s += hbuf[(size_t)b * H_ + n] * Wout[n];
    for (int off = 32; off; off >>= 1) s += __shfl_down(s, off);
    __shared__ float red[4];
    if ((threadIdx.x & 63) == 0) red[threadIdx.x >> 6] = s;
    __syncthreads();
    if (threadIdx.x == 0) {
        float t = red[0] + red[1] + red[2] + red[3] + bout[0];
        out[b] = 1.f / (1.f + expf(-t));
    }
}

extern "C" void kernel_launch(void* const* d_in, const int* in_sizes, int n_in,
                              void* d_out, int out_size, void* d_ws, size_t ws_size,
                              hipStream_t stream) {
    const float* X    = (const float*)d_in[0];
    const float* Mm   = (const float*)d_in[1];
    const float* xm   = (const float*)d_in[2];
    const float* gx   = (const float*)d_in[3];
    const float* Wz   = (const float*)d_in[4];
    const float* bz   = (const float*)d_in[5];
    // d_in[6]=Wr, d_in[7]=br: dead code in reference (r_t unused) — skipped
    const float* Wh   = (const float*)d_in[8];
    const float* bh   = (const float*)d_in[9];
    const float* Wout = (const float*)d_in[10];
    const float* bout = (const float*)d_in[11];
    float* out = (float*)d_out;

    char* ws = (char*)d_ws;
    unsigned short* Wb    = (unsigned short*)(ws + OFF_WB);
    float*          cvec  = (float*)(ws + OFF_CVEC);
    float*          hbuf  = (float*)(ws + OFF_H);
    unsigned short* inp2  = (unsigned short*)(ws + OFF_INP2);
    unsigned short* gates = (unsigned short*)(ws + OFF_GATES);

    build_wb  <<<dim3(N2 * K2 / 256), dim3(256), 0, stream>>>(Wz, Wh, Wb);
    build_cvec<<<dim3(N2),            dim3(256), 0, stream>>>(Wz, bz, Wh, bh, xm, cvec);

    for (int c = 0; c < NCHUNK; c++) {
        build_inp2<<<dim3(TC * B_ * 64 / 256), dim3(256), 0, stream>>>(X, Mm, xm, gx, inp2, c);
        gemm_gates<<<dim3(TC * B_ / 128, 8),   dim3(256), 0, stream>>>(inp2, Wb, cvec, gates);
        recurrence<<<dim3(B_ * H_ / 2 / 256),  dim3(256), 0, stream>>>(gates, hbuf, c == 0 ? 1 : 0);
    }

    head<<<dim3(B_), dim3(256), 0, stream>>>(hbuf, Wout, bout, out);
}

// Round 5
// 940.281 us; speedup vs baseline: 5.6348x; 1.0094x over previous
//
#include <hip/hip_runtime.h>
#include <cstdint>
#include <cstddef>

// Problem constants
#define B_  512
#define T_  256
#define D_  256
#define H_  1024
#define K2  512      // effective K = 2*D (x_tilde | m); xm middle third folded into cvec
#define N2  2048     // stacked outputs: [0,1024)=z preact, [1024,2048)=h_til preact
#define TC  32       // timesteps per chunk
#define NCHUNK 8     // TC*NCHUNK == T_

// Workspace layout (bytes). Total ~88 MB.
#define OFF_WB    ((size_t)0)                      // bf16 [2048][512]            2 MB
#define OFF_CVEC  ((size_t)2097152)                // f32  [2048]                 8 KB
#define OFF_H     ((size_t)2105344)                // f32  [B][H]                 2 MB
#define OFF_INP2  ((size_t)4202496)                // bf16 [TC*B][512]           16 MB
#define OFF_GATES ((size_t)20979712)               // bf16 [TC*B][2048]          64 MB

typedef short   bf16x8 __attribute__((ext_vector_type(8)));   // 8 bf16 (4 VGPRs)
typedef float   f32x4  __attribute__((ext_vector_type(4)));

__device__ __forceinline__ unsigned short f2bf(float f) {
    unsigned int u = __float_as_uint(f);
    u += 0x7fffu + ((u >> 16) & 1u);   // round-to-nearest-even
    return (unsigned short)(u >> 16);
}
__device__ __forceinline__ float bf2f(unsigned short s) {
    return __uint_as_float(((unsigned int)s) << 16);
}
__device__ __forceinline__ void async16(const void* g, void* l) {
    __builtin_amdgcn_global_load_lds(
        (const __attribute__((address_space(1))) void*)g,
        (__attribute__((address_space(3))) void*)l, 16, 0, 0);
}

// ---- Prep: pack effective weight columns [0:D) and [2D:3D) to bf16 [2048][512] ----
__global__ void build_wb(const float* __restrict__ Wz, const float* __restrict__ Wh,
                         unsigned short* __restrict__ Wb) {
    int e = blockIdx.x * 256 + threadIdx.x;
    int r = e >> 9;
    int k = e & 511;
    int col = (k < D_) ? k : (k + D_);             // skip the xm middle third
    float v = (r < H_) ? Wz[(size_t)r * 768 + col]
                       : Wh[(size_t)(r - H_) * 768 + col];
    Wb[e] = f2bf(v);
}

// ---- Prep: cvec[r] = bias[r] + W[r, D:2D] . xm ----
__global__ void build_cvec(const float* __restrict__ Wz, const float* __restrict__ bz,
                           const float* __restrict__ Wh, const float* __restrict__ bh,
                           const float* __restrict__ xm, float* __restrict__ cvec) {
    int r = blockIdx.x;           // 0..2047
    int d = threadIdx.x;          // 0..255
    const float* W = (r < H_) ? (Wz + (size_t)r * 768) : (Wh + (size_t)(r - H_) * 768);
    float v = W[D_ + d] * xm[d];
    for (int off = 32; off; off >>= 1) v += __shfl_down(v, off);
    __shared__ float red[4];
    if ((d & 63) == 0) red[d >> 6] = v;
    __syncthreads();
    if (d == 0) {
        float bias = (r < H_) ? bz[r] : bh[r - H_];
        cvec[r] = bias + red[0] + red[1] + red[2] + red[3];
    }
}

// ---- Per-chunk: build bf16 inp2 rows (r = tc*B + b): [x_tilde(0:256) | m(0:256)] ----
__global__ void build_inp2(const float* __restrict__ X, const float* __restrict__ Mm,
                           const float* __restrict__ xm, const float* __restrict__ gx,
                           unsigned short* __restrict__ inp2, int chunk) {
    int g = blockIdx.x * 256 + threadIdx.x;        // vec8 id; total TC*B*64
    int r = g >> 6;
    int k = (g & 63) * 8;
    int tc = r >> 9;
    int b  = r & (B_ - 1);
    int t  = chunk * TC + tc;
    unsigned short o[8];
    if (k < D_) {
        int d = k;
        const float4* xp = (const float4*)(X  + ((size_t)b * T_ + t) * D_ + d);
        const float4* mp = (const float4*)(Mm + ((size_t)b * T_ + t) * D_ + d);
        float xs[8], ms[8];
        float4 v;
        v = xp[0]; xs[0]=v.x; xs[1]=v.y; xs[2]=v.z; xs[3]=v.w;
        v = xp[1]; xs[4]=v.x; xs[5]=v.y; xs[6]=v.z; xs[7]=v.w;
        v = mp[0]; ms[0]=v.x; ms[1]=v.y; ms[2]=v.z; ms[3]=v.w;
        v = mp[1]; ms[4]=v.x; ms[5]=v.y; ms[6]=v.z; ms[7]=v.w;
        #pragma unroll
        for (int j = 0; j < 8; j++) {
            float m = ms[j], x = xs[j], mu = xm[d + j], gg = gx[d + j];
            float xh = m * x + (1.f - m) * mu;
            float gd = __expf(-gg * (1.f - m));
            o[j] = f2bf(gd * xh + (1.f - gd) * mu);
        }
    } else {
        int d = k - D_;
        const float4* mp = (const float4*)(Mm + ((size_t)b * T_ + t) * D_ + d);
        float4 m0 = mp[0], m1 = mp[1];
        o[0]=f2bf(m0.x); o[1]=f2bf(m0.y); o[2]=f2bf(m0.z); o[3]=f2bf(m0.w);
        o[4]=f2bf(m1.x); o[5]=f2bf(m1.y); o[6]=f2bf(m1.z); o[7]=f2bf(m1.w);
    }
    uint4 pk;
    pk.x = (unsigned)o[0] | ((unsigned)o[1] << 16);
    pk.y = (unsigned)o[2] | ((unsigned)o[3] << 16);
    pk.z = (unsigned)o[4] | ((unsigned)o[5] << 16);
    pk.w = (unsigned)o[6] | ((unsigned)o[7] << 16);
    *(uint4*)(inp2 + (size_t)r * K2 + k) = pk;
}

// ---- GEMM: gates[r][n] = act(inp2[r,:] . Wb[n,:] + cvec[n]) ----
// r3 structure (128x128 tile, BK=32, 16x16x32 MFMA, LDS-roundtrip epilogue)
// + DOUBLE-BUFFERED staging with raw s_barrier: per K-iter
//   [s_waitcnt vmcnt(0) for loads issued ONE ITER AGO] [s_barrier]
//   [issue k+1 -> other buffer] [ds_read + MFMA].
// Avoids __syncthreads' forced full drain at the point where loads were just
// issued (r3/r4 were drain-latency-bound: MfmaUtil*dur constant ~13.4us).
// grid = (Mrows/128, 16); tn<8 -> sigmoid (z), tn>=8 -> tanh (h_til).
__global__ __launch_bounds__(256) void gemm_gates(
    const unsigned short* __restrict__ A,      // [TC*B][512] bf16
    const unsigned short* __restrict__ W,      // [2048][512] bf16
    const float* __restrict__ cvec,            // [2048]
    unsigned short* __restrict__ gates)        // [TC*B][2048] bf16
{
    // two 16 KB staging buffers (As 8K + Bs 8K each); epilogue Cs overlays 16.9 KB
    __shared__ __align__(16) char smem[32768];
    float* Cs = (float*)smem;

    const int tid  = threadIdx.x;
    const int lane = tid & 63;
    const int w    = tid >> 6;
    const int tm = blockIdx.x, tn = blockIdx.y;
    const int wm = w & 1, wn = w >> 1;

    // staging: 8 segments of 16 rows x 32 cols (1 KB each); wave w does segs {2w, 2w+1}
    const int seg  = w * 2;
    const int srow = seg * 16 + (lane >> 2);
    const int scol = (lane & 3) * 8;
    const unsigned short* aptr = A + (size_t)(tm * 128 + srow) * K2 + scol;
    const unsigned short* bptr = W + (size_t)(tn * 128 + srow) * K2 + scol;
    const int adoff = seg * 512;            // shorts, within As of a buffer

    f32x4 acc[4][4] = {};

    // stage K-tile k0 into buffer buf
    auto stage = [&](int k0, int buf) {
        unsigned short* Asb = (unsigned short*)(smem + (buf << 14));
        unsigned short* Bsb = Asb + 4096;
        unsigned short* ad = Asb + adoff;
        unsigned short* bd = Bsb + adoff;
        const int kk = k0 * 32;
        async16(aptr + kk,           ad);
        async16(aptr + 16*K2 + kk,   ad + 512);
        async16(bptr + kk,           bd);
        async16(bptr + 16*K2 + kk,   bd + 512);
    };

    stage(0, 0);                     // prologue: 4 loads in flight for k0=0
    for (int k0 = 0; k0 < 16; k0++) {
        // my loads for THIS iter were issued one iteration ago -> residual wait only
        asm volatile("s_waitcnt vmcnt(0)" ::: "memory");
        // rendezvous: everyone's loads for this iter landed; everyone done
        // reading the other buffer (their previous iter's MFMA consumed it)
        asm volatile("s_barrier" ::: "memory");
        if (k0 < 15) stage(k0 + 1, (k0 + 1) & 1);   // wave-uniform branch
        unsigned short* Asb = (unsigned short*)(smem + ((k0 & 1) << 14));
        unsigned short* Bsb = Asb + 4096;
        bf16x8 af[4], bfr[4];
        #pragma unroll
        for (int i = 0; i < 4; i++)
            af[i]  = *(const bf16x8*)&Asb[(wm*64 + i*16 + (lane & 15)) * 32 + (lane >> 4) * 8];
        #pragma unroll
        for (int j = 0; j < 4; j++)
            bfr[j] = *(const bf16x8*)&Bsb[(wn*64 + j*16 + (lane & 15)) * 32 + (lane >> 4) * 8];
        #pragma unroll
        for (int i = 0; i < 4; i++)
            #pragma unroll
            for (int j = 0; j < 4; j++)
                acc[i][j] = __builtin_amdgcn_mfma_f32_16x16x32_bf16(af[i], bfr[j], acc[i][j], 0, 0, 0);
    }

    const bool is_z = (tn < 8);        // block-uniform: which activation
    const int rl  = tid >> 3;          // 0..31  (read-side row within pass)
    const int cb  = (tid & 7) * 16;    // 0..112 (read-side col base, 16 floats)
    #pragma unroll
    for (int p = 0; p < 4; p++) {      // fully unrolled: acc indices constant
        __syncthreads();               // also protects staging-buffer reuse on p==0
        if (wm == (p >> 1)) {
            #pragma unroll
            for (int il = 0; il < 2; il++) {
                const int i = (p & 1) * 2 + il;
                #pragma unroll
                for (int j = 0; j < 4; j++) {
                    const int col = wn * 64 + j * 16 + (lane & 15);
                    const int rb  = il * 16 + (lane >> 4) * 4;
                    #pragma unroll
                    for (int r = 0; r < 4; r++)
                        Cs[(rb + r) * 132 + col] = acc[i][j][r];
                }
            }
        }
        __syncthreads();
        // read 32x128 fp32, add cvec, activate, pack bf16, coalesced store
        unsigned short tmp[16];
        #pragma unroll
        for (int k = 0; k < 4; k++) {
            f32x4  v  = *(const f32x4*)&Cs[rl * 132 + cb + k * 4];
            float4 cv = *(const float4*)&cvec[tn * 128 + cb + k * 4];
            float vv[4] = { v[0] + cv.x, v[1] + cv.y, v[2] + cv.z, v[3] + cv.w };
            #pragma unroll
            for (int e = 0; e < 4; e++) {
                float u = vv[e];
                if (is_z) u = 1.f / (1.f + __expf(-u));
                else      u = 2.f / (1.f + __expf(-2.f * u)) - 1.f;
                tmp[k * 4 + e] = f2bf(u);
            }
        }
        uint4 pk0, pk1;
        pk0.x = (unsigned)tmp[0]  | ((unsigned)tmp[1]  << 16);
        pk0.y = (unsigned)tmp[2]  | ((unsigned)tmp[3]  << 16);
        pk0.z = (unsigned)tmp[4]  | ((unsigned)tmp[5]  << 16);
        pk0.w = (unsigned)tmp[6]  | ((unsigned)tmp[7]  << 16);
        pk1.x = (unsigned)tmp[8]  | ((unsigned)tmp[9]  << 16);
        pk1.y = (unsigned)tmp[10] | ((unsigned)tmp[11] << 16);
        pk1.z = (unsigned)tmp[12] | ((unsigned)tmp[13] << 16);
        pk1.w = (unsigned)tmp[14] | ((unsigned)tmp[15] << 16);
        const int grow = tm * 128 + p * 32 + rl;
        unsigned short* gp = gates + (size_t)grow * N2 + tn * 128 + cb;
        *(uint4*)gp       = pk0;
        *(uint4*)(gp + 8) = pk1;
    }
}

// ---- Per-chunk elementwise scan: h = (1-z)*h + z*h_til over TC steps ----
__global__ void recurrence(const unsigned short* __restrict__ gates,
                           float* __restrict__ hbuf, int first) {
    const int g  = blockIdx.x * 256 + threadIdx.x;   // B*H/2 threads
    const int b  = g >> 9;
    const int nb = (g & 511) * 2;
    float h0, h1;
    if (first) { h0 = 0.f; h1 = 0.f; }
    else { float2 hv = *(const float2*)&hbuf[(size_t)b * H_ + nb]; h0 = hv.x; h1 = hv.y; }
    for (int tc = 0; tc < TC; tc++) {
        const unsigned short* base = gates + (size_t)(tc * B_ + b) * N2;
        unsigned int zz = *(const unsigned int*)(base + nb);
        unsigned int hh = *(const unsigned int*)(base + H_ + nb);
        float z0 = bf2f((unsigned short)(zz & 0xffff));
        float z1 = bf2f((unsigned short)(zz >> 16));
        float t0 = bf2f((unsigned short)(hh & 0xffff));
        float t1 = bf2f((unsigned short)(hh >> 16));
        h0 = (1.f - z0) * h0 + z0 * t0;
        h1 = (1.f - z1) * h1 + z1 * t1;
    }
    *(float2*)&hbuf[(size_t)b * H_ + nb] = make_float2(h0, h1);
}

// ---- Output head: out[b] = sigmoid(h[b,:] . Wout + bout) ----
__global__ void head(const float* __restrict__ hbuf, const float* __restrict__ Wout,
                     const float* __restrict__ bout, float* __restrict__ out) {
    int b = blockIdx.x;
    float s = 0.f;
    for (int n = threadIdx.x; n < H_; n += 256)
        s += hbuf[(size_t)b * H_ + n] * Wout[n];
    for (int off = 32; off; off >>= 1) s += __shfl_down(s, off);
    __shared__ float red[4];
    if ((threadIdx.x & 63) == 0) red[threadIdx.x >> 6] = s;
    __syncthreads();
    if (threadIdx.x == 0) {
        float t = red[0] + red[1] + red[2] + red[3] + bout[0];
        out[b] = 1.f / (1.f + expf(-t));
    }
}

extern "C" void kernel_launch(void* const* d_in, const int* in_sizes, int n_in,
                              void* d_out, int out_size, void* d_ws, size_t ws_size,
                              hipStream_t stream) {
    const float* X    = (const float*)d_in[0];
    const float* Mm   = (const float*)d_in[1];
    const float* xm   = (const float*)d_in[2];
    const float* gx   = (const float*)d_in[3];
    const float* Wz   = (const float*)d_in[4];
    const float* bz   = (const float*)d_in[5];
    // d_in[6]=Wr, d_in[7]=br: dead code in reference (r_t unused) — skipped
    const float* Wh   = (const float*)d_in[8];
    const float* bh   = (const float*)d_in[9];
    const float* Wout = (const float*)d_in[10];
    const float* bout = (const float*)d_in[11];
    float* out = (float*)d_out;

    char* ws = (char*)d_ws;
    unsigned short* Wb    = (unsigned short*)(ws + OFF_WB);
    float*          cvec  = (float*)(ws + OFF_CVEC);
    float*          hbuf  = (float*)(ws + OFF_H);
    unsigned short* inp2  = (unsigned short*)(ws + OFF_INP2);
    unsigned short* gates = (unsigned short*)(ws + OFF_GATES);

    build_wb  <<<dim3(N2 * K2 / 256), dim3(256), 0, stream>>>(Wz, Wh, Wb);
    build_cvec<<<dim3(N2),            dim3(256), 0, stream>>>(Wz, bz, Wh, bh, xm, cvec);

    for (int c = 0; c < NCHUNK; c++) {
        build_inp2<<<dim3(TC * B_ * 64 / 256), dim3(256), 0, stream>>>(X, Mm, xm, gx, inp2, c);
        gemm_gates<<<dim3(TC * B_ / 128, 16),  dim3(256), 0, stream>>>(inp2, Wb, cvec, gates);
        recurrence<<<dim3(B_ * H_ / 2 / 256),  dim3(256), 0, stream>>>(gates, hbuf, c == 0 ? 1 : 0);
    }

    head<<<dim3(B_), dim3(256), 0, stream>>>(hbuf, Wout, bout, out);
}

// Round 6
// 921.469 us; speedup vs baseline: 5.7499x; 1.0204x over previous
//
#include <hip/hip_runtime.h>
#include <cstdint>
#include <cstddef>

// Problem constants
#define B_  512
#define T_  256
#define D_  256
#define H_  1024
#define K2  512      // effective K = 2*D (x_tilde | m); xm middle third folded into cvec
#define N2  2048     // stacked outputs: [0,1024)=z preact, [1024,2048)=h_til preact
#define TC  32       // timesteps per chunk
#define NCHUNK 8     // TC*NCHUNK == T_

// Workspace layout (bytes). Total ~88 MB (ws is ~512 MiB per round-5 poison fill).
#define OFF_WB    ((size_t)0)                      // bf16 [2048][512]            2 MB
#define OFF_CVEC  ((size_t)2097152)                // f32  [2048]                 8 KB
#define OFF_H     ((size_t)2105344)                // f32  [B][H]                 2 MB
#define OFF_INP2  ((size_t)4202496)                // bf16 [TC*B][512]           16 MB
#define OFF_GATES ((size_t)20979712)               // bf16 [TC*B][2048]          64 MB

typedef short   bf16x8 __attribute__((ext_vector_type(8)));   // 8 bf16 (4 VGPRs)
typedef float   f32x4  __attribute__((ext_vector_type(4)));

__device__ __forceinline__ unsigned short f2bf(float f) {
    unsigned int u = __float_as_uint(f);
    u += 0x7fffu + ((u >> 16) & 1u);   // round-to-nearest-even
    return (unsigned short)(u >> 16);
}
__device__ __forceinline__ float bf2f(unsigned short s) {
    return __uint_as_float(((unsigned int)s) << 16);
}
__device__ __forceinline__ void async16(const void* g, void* l) {
    __builtin_amdgcn_global_load_lds(
        (const __attribute__((address_space(1))) void*)g,
        (__attribute__((address_space(3))) void*)l, 16, 0, 0);
}

// ---- Prep: pack effective weight columns [0:D) and [2D:3D) to bf16 [2048][512] ----
__global__ void build_wb(const float* __restrict__ Wz, const float* __restrict__ Wh,
                         unsigned short* __restrict__ Wb) {
    int e = blockIdx.x * 256 + threadIdx.x;
    int r = e >> 9;
    int k = e & 511;
    int col = (k < D_) ? k : (k + D_);             // skip the xm middle third
    float v = (r < H_) ? Wz[(size_t)r * 768 + col]
                       : Wh[(size_t)(r - H_) * 768 + col];
    Wb[e] = f2bf(v);
}

// ---- Prep: cvec[r] = bias[r] + W[r, D:2D] . xm ----
__global__ void build_cvec(const float* __restrict__ Wz, const float* __restrict__ bz,
                           const float* __restrict__ Wh, const float* __restrict__ bh,
                           const float* __restrict__ xm, float* __restrict__ cvec) {
    int r = blockIdx.x;           // 0..2047
    int d = threadIdx.x;          // 0..255
    const float* W = (r < H_) ? (Wz + (size_t)r * 768) : (Wh + (size_t)(r - H_) * 768);
    float v = W[D_ + d] * xm[d];
    for (int off = 32; off; off >>= 1) v += __shfl_down(v, off);
    __shared__ float red[4];
    if ((d & 63) == 0) red[d >> 6] = v;
    __syncthreads();
    if (d == 0) {
        float bias = (r < H_) ? bz[r] : bh[r - H_];
        cvec[r] = bias + red[0] + red[1] + red[2] + red[3];
    }
}

// ---- Per-chunk: build bf16 inp2 rows (r = tc*B + b): [x_tilde(0:256) | m(0:256)] ----
__global__ void build_inp2(const float* __restrict__ X, const float* __restrict__ Mm,
                           const float* __restrict__ xm, const float* __restrict__ gx,
                           unsigned short* __restrict__ inp2, int chunk) {
    int g = blockIdx.x * 256 + threadIdx.x;        // vec8 id; total TC*B*64
    int r = g >> 6;
    int k = (g & 63) * 8;
    int tc = r >> 9;
    int b  = r & (B_ - 1);
    int t  = chunk * TC + tc;
    unsigned short o[8];
    if (k < D_) {
        int d = k;
        const float4* xp = (const float4*)(X  + ((size_t)b * T_ + t) * D_ + d);
        const float4* mp = (const float4*)(Mm + ((size_t)b * T_ + t) * D_ + d);
        float xs[8], ms[8];
        float4 v;
        v = xp[0]; xs[0]=v.x; xs[1]=v.y; xs[2]=v.z; xs[3]=v.w;
        v = xp[1]; xs[4]=v.x; xs[5]=v.y; xs[6]=v.z; xs[7]=v.w;
        v = mp[0]; ms[0]=v.x; ms[1]=v.y; ms[2]=v.z; ms[3]=v.w;
        v = mp[1]; ms[4]=v.x; ms[5]=v.y; ms[6]=v.z; ms[7]=v.w;
        #pragma unroll
        for (int j = 0; j < 8; j++) {
            float m = ms[j], x = xs[j], mu = xm[d + j], gg = gx[d + j];
            float xh = m * x + (1.f - m) * mu;
            float gd = __expf(-gg * (1.f - m));
            o[j] = f2bf(gd * xh + (1.f - gd) * mu);
        }
    } else {
        int d = k - D_;
        const float4* mp = (const float4*)(Mm + ((size_t)b * T_ + t) * D_ + d);
        float4 m0 = mp[0], m1 = mp[1];
        o[0]=f2bf(m0.x); o[1]=f2bf(m0.y); o[2]=f2bf(m0.z); o[3]=f2bf(m0.w);
        o[4]=f2bf(m1.x); o[5]=f2bf(m1.y); o[6]=f2bf(m1.z); o[7]=f2bf(m1.w);
    }
    uint4 pk;
    pk.x = (unsigned)o[0] | ((unsigned)o[1] << 16);
    pk.y = (unsigned)o[2] | ((unsigned)o[3] << 16);
    pk.z = (unsigned)o[4] | ((unsigned)o[5] << 16);
    pk.w = (unsigned)o[6] | ((unsigned)o[7] << 16);
    *(uint4*)(inp2 + (size_t)r * K2 + k) = pk;
}

// ---- GEMM: gates[r][n] = act(inp2[r,:] . Wb[n,:] + cvec[n]) ----
// 128x128 tile, BK=32, 16x16x32 MFMA, LDS-roundtrip epilogue.
// DEPTH-3 pipelined staging (AITER-style, never wait vmcnt to 0 mid-loop):
//   iter k: [s_waitcnt vmcnt(4): tile k landed, issued 2 iters (~340cyc) ago;
//            tiles k+1,k+2 stay in flight] [s_barrier]
//           [stage tile k+2 into buf (k+2)%3 == (k-1)%3, safe: its reads
//            completed before this barrier] [ds_read buf k%3 + MFMA].
// r5 (depth-1, vmcnt(0)) covered only ~170cyc of ~200-500cyc L2/L3 latency.
// grid = (Mrows/128, 16); tn<8 -> sigmoid (z), tn>=8 -> tanh (h_til).
__global__ __launch_bounds__(256) void gemm_gates(
    const unsigned short* __restrict__ A,      // [TC*B][512] bf16
    const unsigned short* __restrict__ W,      // [2048][512] bf16
    const float* __restrict__ cvec,            // [2048]
    unsigned short* __restrict__ gates)        // [TC*B][2048] bf16
{
    // 3 x 16 KB staging buffers; epilogue Cs overlays first 16.9 KB
    __shared__ __align__(16) char smem[49152];
    float* Cs = (float*)smem;

    const int tid  = threadIdx.x;
    const int lane = tid & 63;
    const int w    = tid >> 6;
    const int tm = blockIdx.x, tn = blockIdx.y;
    const int wm = w & 1, wn = w >> 1;

    // staging: 8 segments of 16 rows x 32 cols (1 KB each); wave w does segs {2w, 2w+1}
    const int seg  = w * 2;
    const int srow = seg * 16 + (lane >> 2);
    const int scol = (lane & 3) * 8;
    const unsigned short* aptr = A + (size_t)(tm * 128 + srow) * K2 + scol;
    const unsigned short* bptr = W + (size_t)(tn * 128 + srow) * K2 + scol;
    const int adoff = seg * 512;            // shorts, within As of a buffer

    f32x4 acc[4][4] = {};

    // stage K-tile t into buffer buf (buf in 0..2)
    auto stage = [&](int t, int buf) {
        unsigned short* Asb = (unsigned short*)(smem + buf * 16384);
        unsigned short* Bsb = Asb + 4096;
        unsigned short* ad = Asb + adoff;
        unsigned short* bd = Bsb + adoff;
        const int kk = t * 32;
        async16(aptr + kk,           ad);
        async16(aptr + 16*K2 + kk,   ad + 512);
        async16(bptr + kk,           bd);
        async16(bptr + 16*K2 + kk,   bd + 512);
    };

    stage(0, 0);                     // prologue: tiles 0,1 in flight (8 loads)
    stage(1, 1);
    int buf = 0;                     // buf == k0 % 3, maintained incrementally
    int nbuf = 2;                    // (k0+2) % 3
    for (int k0 = 0; k0 < 16; k0++) {
        // tile k0's 4 loads are the oldest outstanding; tiles k0+1,k0+2 (<=8 loads) stay in flight
        if (k0 < 15) { asm volatile("s_waitcnt vmcnt(4)" ::: "memory"); }
        else         { asm volatile("s_waitcnt vmcnt(0)" ::: "memory"); }
        asm volatile("s_barrier" ::: "memory");
        if (k0 < 14) stage(k0 + 2, nbuf);   // wave-uniform branch
        unsigned short* Asb = (unsigned short*)(smem + buf * 16384);
        unsigned short* Bsb = Asb + 4096;
        bf16x8 af[4], bfr[4];
        #pragma unroll
        for (int i = 0; i < 4; i++)
            af[i]  = *(const bf16x8*)&Asb[(wm*64 + i*16 + (lane & 15)) * 32 + (lane >> 4) * 8];
        #pragma unroll
        for (int j = 0; j < 4; j++)
            bfr[j] = *(const bf16x8*)&Bsb[(wn*64 + j*16 + (lane & 15)) * 32 + (lane >> 4) * 8];
        #pragma unroll
        for (int i = 0; i < 4; i++)
            #pragma unroll
            for (int j = 0; j < 4; j++)
                acc[i][j] = __builtin_amdgcn_mfma_f32_16x16x32_bf16(af[i], bfr[j], acc[i][j], 0, 0, 0);
        buf  = (buf  == 2) ? 0 : buf  + 1;
        nbuf = (nbuf == 2) ? 0 : nbuf + 1;
    }

    const bool is_z = (tn < 8);        // block-uniform: which activation
    const int rl  = tid >> 3;          // 0..31  (read-side row within pass)
    const int cb  = (tid & 7) * 16;    // 0..112 (read-side col base, 16 floats)
    #pragma unroll
    for (int p = 0; p < 4; p++) {      // fully unrolled: acc indices constant
        __syncthreads();               // also protects staging-buffer reuse on p==0
        if (wm == (p >> 1)) {
            #pragma unroll
            for (int il = 0; il < 2; il++) {
                const int i = (p & 1) * 2 + il;
                #pragma unroll
                for (int j = 0; j < 4; j++) {
                    const int col = wn * 64 + j * 16 + (lane & 15);
                    const int rb  = il * 16 + (lane >> 4) * 4;
                    #pragma unroll
                    for (int r = 0; r < 4; r++)
                        Cs[(rb + r) * 132 + col] = acc[i][j][r];
                }
            }
        }
        __syncthreads();
        // read 32x128 fp32, add cvec, activate, pack bf16, coalesced store
        unsigned short tmp[16];
        #pragma unroll
        for (int k = 0; k < 4; k++) {
            f32x4  v  = *(const f32x4*)&Cs[rl * 132 + cb + k * 4];
            float4 cv = *(const float4*)&cvec[tn * 128 + cb + k * 4];
            float vv[4] = { v[0] + cv.x, v[1] + cv.y, v[2] + cv.z, v[3] + cv.w };
            #pragma unroll
            for (int e = 0; e < 4; e++) {
                float u = vv[e];
                if (is_z) u = 1.f / (1.f + __expf(-u));
                else      u = 2.f / (1.f + __expf(-2.f * u)) - 1.f;
                tmp[k * 4 + e] = f2bf(u);
            }
        }
        uint4 pk0, pk1;
        pk0.x = (unsigned)tmp[0]  | ((unsigned)tmp[1]  << 16);
        pk0.y = (unsigned)tmp[2]  | ((unsigned)tmp[3]  << 16);
        pk0.z = (unsigned)tmp[4]  | ((unsigned)tmp[5]  << 16);
        pk0.w = (unsigned)tmp[6]  | ((unsigned)tmp[7]  << 16);
        pk1.x = (unsigned)tmp[8]  | ((unsigned)tmp[9]  << 16);
        pk1.y = (unsigned)tmp[10] | ((unsigned)tmp[11] << 16);
        pk1.z = (unsigned)tmp[12] | ((unsigned)tmp[13] << 16);
        pk1.w = (unsigned)tmp[14] | ((unsigned)tmp[15] << 16);
        const int grow = tm * 128 + p * 32 + rl;
        unsigned short* gp = gates + (size_t)grow * N2 + tn * 128 + cb;
        *(uint4*)gp       = pk0;
        *(uint4*)(gp + 8) = pk1;
    }
}

// ---- Per-chunk elementwise scan: h = (1-z)*h + z*h_til over TC steps ----
__global__ void recurrence(const unsigned short* __restrict__ gates,
                           float* __restrict__ hbuf, int first) {
    const int g  = blockIdx.x * 256 + threadIdx.x;   // B*H/2 threads
    const int b  = g >> 9;
    const int nb = (g & 511) * 2;
    float h0, h1;
    if (first) { h0 = 0.f; h1 = 0.f; }
    else { float2 hv = *(const float2*)&hbuf[(size_t)b * H_ + nb]; h0 = hv.x; h1 = hv.y; }
    for (int tc = 0; tc < TC; tc++) {
        const unsigned short* base = gates + (size_t)(tc * B_ + b) * N2;
        unsigned int zz = *(const unsigned int*)(base + nb);
        unsigned int hh = *(const unsigned int*)(base + H_ + nb);
        float z0 = bf2f((unsigned short)(zz & 0xffff));
        float z1 = bf2f((unsigned short)(zz >> 16));
        float t0 = bf2f((unsigned short)(hh & 0xffff));
        float t1 = bf2f((unsigned short)(hh >> 16));
        h0 = (1.f - z0) * h0 + z0 * t0;
        h1 = (1.f - z1) * h1 + z1 * t1;
    }
    *(float2*)&hbuf[(size_t)b * H_ + nb] = make_float2(h0, h1);
}

// ---- Output head: out[b] = sigmoid(h[b,:] . Wout + bout) ----
__global__ void head(const float* __restrict__ hbuf, const float* __restrict__ Wout,
                     const float* __restrict__ bout, float* __restrict__ out) {
    int b = blockIdx.x;
    float s = 0.f;
    for (int n = threadIdx.x; n < H_; n += 256)
        s += hbuf[(size_t)b * H_ + n] * Wout[n];
    for (int off = 32; off; off >>= 1) s += __shfl_down(s, off);
    __shared__ float red[4];
    if ((threadIdx.x & 63) == 0) red[threadIdx.x >> 6] = s;
    __syncthreads();
    if (threadIdx.x == 0) {
        float t = red[0] + red[1] + red[2] + red[3] + bout[0];
        out[b] = 1.f / (1.f + expf(-t));
    }
}

extern "C" void kernel_launch(void* const* d_in, const int* in_sizes, int n_in,
                              void* d_out, int out_size, void* d_ws, size_t ws_size,
                              hipStream_t stream) {
    const float* X    = (const float*)d_in[0];
    const float* Mm   = (const float*)d_in[1];
    const float* xm   = (const float*)d_in[2];
    const float* gx   = (const float*)d_in[3];
    const float* Wz   = (const float*)d_in[4];
    const float* bz   = (const float*)d_in[5];
    // d_in[6]=Wr, d_in[7]=br: dead code in reference (r_t unused) — skipped
    const float* Wh   = (const float*)d_in[8];
    const float* bh   = (const float*)d_in[9];
    const float* Wout = (const float*)d_in[10];
    const float* bout = (const float*)d_in[11];
    float* out = (float*)d_out;

    char* ws = (char*)d_ws;
    unsigned short* Wb    = (unsigned short*)(ws + OFF_WB);
    float*          cvec  = (float*)(ws + OFF_CVEC);
    float*          hbuf  = (float*)(ws + OFF_H);
    unsigned short* inp2  = (unsigned short*)(ws + OFF_INP2);
    unsigned short* gates = (unsigned short*)(ws + OFF_GATES);

    build_wb  <<<dim3(N2 * K2 / 256), dim3(256), 0, stream>>>(Wz, Wh, Wb);
    build_cvec<<<dim3(N2),            dim3(256), 0, stream>>>(Wz, bz, Wh, bh, xm, cvec);

    for (int c = 0; c < NCHUNK; c++) {
        build_inp2<<<dim3(TC * B_ * 64 / 256), dim3(256), 0, stream>>>(X, Mm, xm, gx, inp2, c);
        gemm_gates<<<dim3(TC * B_ / 128, 16),  dim3(256), 0, stream>>>(inp2, Wb, cvec, gates);
        recurrence<<<dim3(B_ * H_ / 2 / 256),  dim3(256), 0, stream>>>(gates, hbuf, c == 0 ? 1 : 0);
    }

    head<<<dim3(B_), dim3(256), 0, stream>>>(hbuf, Wout, bout, out);
}